// Round 1
// baseline (387.061 us; speedup 1.0000x reference)
//
#include <hip/hip_runtime.h>

// SpatialTransformer 3D warp, B=2 C=1 D=160 H=192 W=224, fp32 in/out.
// Reference semantics:
//   px = (x + flow0 + 1) * 0.5 * (W-1)   (x-channel "unnormalized" from raw coords)
//   py = y + flow1 ; pz = z + flow2
//   trilinear sample of img with border clamp (align_corners=True already folded).

#define Bc   2
#define Dc   160
#define Hc   192
#define Wc   224
#define HWc  (Hc * Wc)          // 43008
#define DHWc (Dc * HWc)         // 6881280
#define TOT  (Bc * DHWc)        // 13762560
#define N4   (TOT / 4)          // 3440640

__global__ __launch_bounds__(256) void st3d_kernel(
    const float* __restrict__ img,
    const float* __restrict__ flow,
    float* __restrict__ out)
{
    int i4 = blockIdx.x * blockDim.x + threadIdx.x;
    if (i4 >= N4) return;
    int i = i4 * 4;

    // decompose flat index (constant divides -> magic multiplies)
    int b = i / DHWc;
    int s = i - b * DHWc;          // spatial index within batch
    int z = s / HWc;
    int r = s - z * HWc;
    int y = r / Wc;
    int x = r - y * Wc;            // 4 | Wc so the float4 stays in one row

    const float* flowb = flow + (size_t)b * 3 * DHWc + s;
    const float4 f0 = *(const float4*)(flowb);
    const float4 f1 = *(const float4*)(flowb + DHWc);
    const float4 f2 = *(const float4*)(flowb + 2 * DHWc);

    float f0a[4] = {f0.x, f0.y, f0.z, f0.w};
    float f1a[4] = {f1.x, f1.y, f1.z, f1.w};
    float f2a[4] = {f2.x, f2.y, f2.z, f2.w};

    const float* imgb = img + (size_t)b * DHWc;

    float oa[4];
#pragma unroll
    for (int k = 0; k < 4; ++k) {
        float px = ((float)(x + k) + f0a[k] + 1.0f) * 0.5f * (float)(Wc - 1);
        float py = (float)y + f1a[k];
        float pz = (float)z + f2a[k];
        px = fminf(fmaxf(px, 0.0f), (float)(Wc - 1));
        py = fminf(fmaxf(py, 0.0f), (float)(Hc - 1));
        pz = fminf(fmaxf(pz, 0.0f), (float)(Dc - 1));

        float x0f = floorf(px), y0f = floorf(py), z0f = floorf(pz);
        float fx = px - x0f, fy = py - y0f, fz = pz - z0f;
        int x0 = (int)x0f, y0 = (int)y0f, z0 = (int)z0f;
        int x1 = min(x0 + 1, Wc - 1);
        int y1 = min(y0 + 1, Hc - 1);
        int z1 = min(z0 + 1, Dc - 1);

        const float* pz0 = imgb + z0 * HWc;
        const float* pz1 = imgb + z1 * HWc;
        int r0 = y0 * Wc, r1 = y1 * Wc;

        float c000 = pz0[r0 + x0];
        float c001 = pz0[r0 + x1];
        float c010 = pz0[r1 + x0];
        float c011 = pz0[r1 + x1];
        float c100 = pz1[r0 + x0];
        float c101 = pz1[r0 + x1];
        float c110 = pz1[r1 + x0];
        float c111 = pz1[r1 + x1];

        float c00 = c000 + (c001 - c000) * fx;
        float c01 = c010 + (c011 - c010) * fx;
        float c10 = c100 + (c101 - c100) * fx;
        float c11 = c110 + (c111 - c110) * fx;
        float c0  = c00  + (c01  - c00 ) * fy;
        float c1  = c10  + (c11  - c10 ) * fy;
        oa[k] = c0 + (c1 - c0) * fz;
    }

    float4 o = make_float4(oa[0], oa[1], oa[2], oa[3]);
    *(float4*)(out + i) = o;
}

extern "C" void kernel_launch(void* const* d_in, const int* in_sizes, int n_in,
                              void* d_out, int out_size, void* d_ws, size_t ws_size,
                              hipStream_t stream)
{
    const float* img  = (const float*)d_in[0];
    const float* flow = (const float*)d_in[1];
    float* out = (float*)d_out;

    const int threads = 256;
    const int blocks  = (N4 + threads - 1) / threads;  // 13440
    st3d_kernel<<<blocks, threads, 0, stream>>>(img, flow, out);
}

// Round 2
// 311.797 us; speedup vs baseline: 1.2414x; 1.2414x over previous
//
#include <hip/hip_runtime.h>

// SpatialTransformer 3D warp, B=2 C=1 D=160 H=192 W=224, fp32 in/out.
//   px = clamp((x + flow0 + 1) * 0.5 * (W-1), 0, W-1)   -> fx==0 for ~97.7% of voxels
//   py = clamp(y + flow1, 0, H-1); pz = clamp(z + flow2, 0, D-1)
//   trilinear sample with border clamp. When fx==0 the x1 corners have zero
//   weight -> 4-corner bilinear path (cuts vmem instruction count ~45%;
//   round-1 rocprof showed the kernel is vmem-issue bound: 36 vmem/thread
//   == 484K/CU == 200us @ 1 instr/cy).

#define Bc   2
#define Dc   160
#define Hc   192
#define Wc   224
#define HWc  (Hc * Wc)          // 43008
#define DHWc (Dc * HWc)         // 6881280
#define TOT  (Bc * DHWc)        // 13762560
#define N4   (TOT / 4)          // 3440640

__global__ __launch_bounds__(256) void st3d_kernel(
    const float* __restrict__ img,
    const float* __restrict__ flow,
    float* __restrict__ out)
{
    int i4 = blockIdx.x * blockDim.x + threadIdx.x;
    if (i4 >= N4) return;
    int i = i4 * 4;

    int b = i / DHWc;
    int s = i - b * DHWc;
    int z = s / HWc;
    int r = s - z * HWc;
    int y = r / Wc;
    int x = r - y * Wc;            // 4 | Wc so the float4 stays in one row

    const float* flowb = flow + (size_t)b * 3 * DHWc + s;
    const float4 f0 = *(const float4*)(flowb);
    const float4 f1 = *(const float4*)(flowb + DHWc);
    const float4 f2 = *(const float4*)(flowb + 2 * DHWc);

    float f0a[4] = {f0.x, f0.y, f0.z, f0.w};
    float f1a[4] = {f1.x, f1.y, f1.z, f1.w};
    float f2a[4] = {f2.x, f2.y, f2.z, f2.w};

    const float* imgb = img + (size_t)b * DHWc;

    // per-voxel sample setup
    float fxa[4], fya[4], fza[4];
    int x0a[4], x1a[4];
    int r0a[4], r1a[4];            // y0*W, y1*W
    int zo0a[4], zo1a[4];          // z0*HW, z1*HW
#pragma unroll
    for (int k = 0; k < 4; ++k) {
        float px = ((float)(x + k) + f0a[k] + 1.0f) * (0.5f * (float)(Wc - 1));
        float py = (float)y + f1a[k];
        float pz = (float)z + f2a[k];
        px = fminf(fmaxf(px, 0.0f), (float)(Wc - 1));
        py = fminf(fmaxf(py, 0.0f), (float)(Hc - 1));
        pz = fminf(fmaxf(pz, 0.0f), (float)(Dc - 1));

        float x0f = floorf(px), y0f = floorf(py), z0f = floorf(pz);
        fxa[k] = px - x0f; fya[k] = py - y0f; fza[k] = pz - z0f;
        int x0 = (int)x0f, y0 = (int)y0f, z0 = (int)z0f;
        x0a[k] = x0;
        x1a[k] = min(x0 + 1, Wc - 1);
        int y1 = min(y0 + 1, Hc - 1);
        int z1 = min(z0 + 1, Dc - 1);
        r0a[k] = y0 * Wc;  r1a[k] = y1 * Wc;
        zo0a[k] = z0 * HWc; zo1a[k] = z1 * HWc;
    }

    bool needX1 = (fxa[0] != 0.0f) | (fxa[1] != 0.0f) |
                  (fxa[2] != 0.0f) | (fxa[3] != 0.0f);

    float oa[4];
    if (!needX1) {
        // fx==0 for all 4 voxels: x1 corners have zero weight -> 4 gathers/voxel
#pragma unroll
        for (int k = 0; k < 4; ++k) {
            const float* pz0 = imgb + zo0a[k];
            const float* pz1 = imgb + zo1a[k];
            float c00 = pz0[r0a[k] + x0a[k]];
            float c01 = pz0[r1a[k] + x0a[k]];
            float c10 = pz1[r0a[k] + x0a[k]];
            float c11 = pz1[r1a[k] + x0a[k]];
            float c0 = c00 + (c01 - c00) * fya[k];
            float c1 = c10 + (c11 - c10) * fya[k];
            oa[k] = c0 + (c1 - c0) * fza[k];
        }
    } else {
        // full trilinear: 8 gathers/voxel
#pragma unroll
        for (int k = 0; k < 4; ++k) {
            const float* pz0 = imgb + zo0a[k];
            const float* pz1 = imgb + zo1a[k];
            int r0 = r0a[k], r1 = r1a[k];
            int x0 = x0a[k], x1 = x1a[k];
            float c000 = pz0[r0 + x0];
            float c001 = pz0[r0 + x1];
            float c010 = pz0[r1 + x0];
            float c011 = pz0[r1 + x1];
            float c100 = pz1[r0 + x0];
            float c101 = pz1[r0 + x1];
            float c110 = pz1[r1 + x0];
            float c111 = pz1[r1 + x1];
            float fx = fxa[k], fy = fya[k], fz = fza[k];
            float c00 = c000 + (c001 - c000) * fx;
            float c01 = c010 + (c011 - c010) * fx;
            float c10 = c100 + (c101 - c100) * fx;
            float c11 = c110 + (c111 - c110) * fx;
            float c0  = c00  + (c01  - c00 ) * fy;
            float c1  = c10  + (c11  - c10 ) * fy;
            oa[k] = c0 + (c1 - c0) * fz;
        }
    }

    float4 o = make_float4(oa[0], oa[1], oa[2], oa[3]);
    *(float4*)(out + i) = o;
}

extern "C" void kernel_launch(void* const* d_in, const int* in_sizes, int n_in,
                              void* d_out, int out_size, void* d_ws, size_t ws_size,
                              hipStream_t stream)
{
    const float* img  = (const float*)d_in[0];
    const float* flow = (const float*)d_in[1];
    float* out = (float*)d_out;

    const int threads = 256;
    const int blocks  = (N4 + threads - 1) / threads;  // 13440
    st3d_kernel<<<blocks, threads, 0, stream>>>(img, flow, out);
}

// Round 5
// 284.325 us; speedup vs baseline: 1.3613x; 1.0966x over previous
//
#include <hip/hip_runtime.h>

// SpatialTransformer 3D warp, B=2 C=1 D=160 H=192 W=224, fp32 in/out.
// px = clamp((x+flow0+1)*0.5*223, 0, 223)  -> px==223 exactly for ~97.7% of
// voxels (all x >~ 6). For those, trilinear degenerates to 2D bilinear over the
// x=223 column with corners (z0,y0),(z0+1,y0),(z0,y0+1),(z0+1,y0+1).
// Kernel 1 packs those 4 corners (border-clamped) into one float4 per (b,z,y):
// V4[b][z][y] = {v(z,y), v(zc,y), v(z,yc), v(zc,yc)}  (983 KB in d_ws, L2-resident).
// Kernel 2: bulk blocks (x>=16) do ONE dwordx4 gather per voxel (guarded by a
// wave-uniform __all(px==223) with a full-trilinear fallback for safety);
// strip blocks (x<16) take a per-voxel branch between the V4 path and full
// 8-gather trilinear. Round-2 rocprof showed the cost is L1 line lookups on
// divergent gathers (1 line/cy/CU); this cuts lookups ~4-6x.

#define Wc 224
#define Hc 192
#define Dc 160
#define HWc  (Hc * Wc)          // 43008
#define DHWc (Dc * HWc)         // 6881280
#define NROWS (2 * Dc * Hc)     // 61440 (b,z,y) rows
#define STRIP_X 16
#define STRIP_TPR 4             // threads per row, strip (4 voxels each)
#define BULK_TPR 52             // threads per row, bulk  (x in [16,224))
#define STRIP_BLOCKS ((NROWS * STRIP_TPR) / 256)   // 960
#define BULK_BLOCKS  ((NROWS * BULK_TPR) / 256)    // 12480

__global__ __launch_bounds__(256) void extract_v4(
    const float* __restrict__ img, float4* __restrict__ V4)
{
    int t = blockIdx.x * 256 + threadIdx.x;        // 61440 threads
    int y = t % Hc;
    int zb = t / Hc;
    int z = zb % Dc;
    int b = zb / Dc;
    const float* p = img + (size_t)b * DHWc + z * HWc + y * Wc + (Wc - 1);
    int dz = (z < Dc - 1) ? HWc : 0;
    int dy = (y < Hc - 1) ? Wc : 0;
    V4[t] = make_float4(p[0], p[dz], p[dy], p[dz + dy]);
}

__device__ __forceinline__ float bilinear_v4(const float4* __restrict__ V4b,
                                             float py, float pz)
{
    float y0f = floorf(py), z0f = floorf(pz);
    float fy = py - y0f, fz = pz - z0f;
    int y0 = (int)y0f, z0 = (int)z0f;
    float4 c = V4b[z0 * Hc + y0];     // {c000, c100, c010, c110} at x=223
    float c0 = c.x + (c.z - c.x) * fy;
    float c1 = c.y + (c.w - c.y) * fy;
    return c0 + (c1 - c0) * fz;
}

__device__ __forceinline__ float trilinear_general(const float* __restrict__ imgb,
                                                   float px, float py, float pz)
{
    float x0f = floorf(px), y0f = floorf(py), z0f = floorf(pz);
    float fx = px - x0f, fy = py - y0f, fz = pz - z0f;
    int x0 = (int)x0f, y0 = (int)y0f, z0 = (int)z0f;
    int x1 = min(x0 + 1, Wc - 1);
    int y1 = min(y0 + 1, Hc - 1);
    int z1 = min(z0 + 1, Dc - 1);
    const float* pz0 = imgb + z0 * HWc;
    const float* pz1 = imgb + z1 * HWc;
    int r0 = y0 * Wc, r1 = y1 * Wc;
    float c000 = pz0[r0 + x0], c001 = pz0[r0 + x1];
    float c010 = pz0[r1 + x0], c011 = pz0[r1 + x1];
    float c100 = pz1[r0 + x0], c101 = pz1[r0 + x1];
    float c110 = pz1[r1 + x0], c111 = pz1[r1 + x1];
    float c00 = c000 + (c001 - c000) * fx;
    float c01 = c010 + (c011 - c010) * fx;
    float c10 = c100 + (c101 - c100) * fx;
    float c11 = c110 + (c111 - c110) * fx;
    float c0  = c00  + (c01  - c00 ) * fy;
    float c1  = c10  + (c11  - c10 ) * fy;
    return c0 + (c1 - c0) * fz;
}

__global__ __launch_bounds__(256) void warp3d(
    const float* __restrict__ img,
    const float* __restrict__ flow,
    const float4* __restrict__ V4,
    float* __restrict__ out)
{
    int bid = blockIdx.x;
    int b, z, y, x;
    if (bid < STRIP_BLOCKS) {
        int t = bid * 256 + threadIdx.x;
        int xc = t % STRIP_TPR;  int row = t / STRIP_TPR;
        y = row % Hc;  int zb = row / Hc;  z = zb % Dc;  b = zb / Dc;
        x = xc * 4;
    } else {
        int t = (bid - STRIP_BLOCKS) * 256 + threadIdx.x;
        int xc = t % BULK_TPR;   int row = t / BULK_TPR;
        y = row % Hc;  int zb = row / Hc;  z = zb % Dc;  b = zb / Dc;
        x = STRIP_X + xc * 4;
    }

    int s = z * HWc + y * Wc + x;
    const float* flowb = flow + (size_t)b * 3 * DHWc + s;
    const float4 f0 = *(const float4*)(flowb);
    const float4 f1 = *(const float4*)(flowb + DHWc);
    const float4 f2 = *(const float4*)(flowb + 2 * DHWc);

    float f0a[4] = {f0.x, f0.y, f0.z, f0.w};
    float f1a[4] = {f1.x, f1.y, f1.z, f1.w};
    float f2a[4] = {f2.x, f2.y, f2.z, f2.w};

    const float*  imgb = img + (size_t)b * DHWc;
    const float4* V4b  = V4 + (size_t)b * (Dc * Hc);

    float pxa[4], pya[4], pza[4];
    bool allc = true;
#pragma unroll
    for (int k = 0; k < 4; ++k) {
        float px = ((float)(x + k) + f0a[k] + 1.0f) * (0.5f * (float)(Wc - 1));
        px = fminf(fmaxf(px, 0.0f), (float)(Wc - 1));
        float py = fminf(fmaxf((float)y + f1a[k], 0.0f), (float)(Hc - 1));
        float pz = fminf(fmaxf((float)z + f2a[k], 0.0f), (float)(Dc - 1));
        pxa[k] = px; pya[k] = py; pza[k] = pz;
        allc &= (px == (float)(Wc - 1));
    }

    float oa[4];
    if (__all((int)allc)) {
        // wave-uniform fast path: 1 dwordx4 gather per voxel
#pragma unroll
        for (int k = 0; k < 4; ++k)
            oa[k] = bilinear_v4(V4b, pya[k], pza[k]);
    } else {
        // strip blocks (and adversarial-data safety for bulk)
#pragma unroll
        for (int k = 0; k < 4; ++k) {
            if (pxa[k] == (float)(Wc - 1))
                oa[k] = bilinear_v4(V4b, pya[k], pza[k]);
            else
                oa[k] = trilinear_general(imgb, pxa[k], pya[k], pza[k]);
        }
    }

    *(float4*)(out + (size_t)b * DHWc + s) = make_float4(oa[0], oa[1], oa[2], oa[3]);
}

extern "C" void kernel_launch(void* const* d_in, const int* in_sizes, int n_in,
                              void* d_out, int out_size, void* d_ws, size_t ws_size,
                              hipStream_t stream)
{
    const float* img  = (const float*)d_in[0];
    const float* flow = (const float*)d_in[1];
    float* out = (float*)d_out;
    float4* V4 = (float4*)d_ws;   // 61440 * 16 B = 983 KB

    extract_v4<<<NROWS / 256, 256, 0, stream>>>(img, V4);
    warp3d<<<STRIP_BLOCKS + BULK_BLOCKS, 256, 0, stream>>>(img, flow, V4, out);
}